// Round 1
// baseline (864.199 us; speedup 1.0000x reference)
//
#include <hip/hip_runtime.h>
#include <math.h>

#define SEQ   2048
#define HD    128
#define QB    64
#define KVB   64

typedef __bf16 bf16_t;
typedef __bf16 bf16x4 __attribute__((ext_vector_type(4)));
typedef __bf16 bf16x8 __attribute__((ext_vector_type(8)));
typedef float  f32x4  __attribute__((ext_vector_type(4)));

// Flash-attention forward, fp32 in/out, bf16 MFMA compute.
// Layout facts used (HW-verified per guide):
//   mfma_f32_16x16x32_bf16 C/D: col = lane&15, row = (lane>>4)*4 + reg   [m89]
//   A/B fragments: 8 contiguous reduction-dim elems per lane at k = (lane>>4)*8+j
//   (permutation-safe: both operands use the same slot->k map)
__global__ __launch_bounds__(256, 2)
void attn_fwd(const float* __restrict__ q_g, const float* __restrict__ k_g,
              const float* __restrict__ v_g, const float* __restrict__ m_g,
              float* __restrict__ o_g) {
  // K tile [64][128] bf16 row-major, XOR-swizzled (row&7)<<4  -> 16 KiB
  __shared__ __align__(16) char ldsK[KVB * 256];
  // V^T tile [128 d][64 k] bf16, XOR-swizzled (d&7)<<4        -> 16 KiB
  __shared__ __align__(16) char ldsV[HD * 128];
  // per-wave P [16 q][64 k] bf16, XOR-swizzled (row&7)<<4     -> 8 KiB
  __shared__ __align__(16) char ldsP[4][16 * 128];

  const int tid  = threadIdx.x;
  const int wid  = tid >> 6;      // wave 0..3, owns q rows wid*16..+15
  const int lane = tid & 63;
  const int g    = lane >> 4;     // 4-lane-group id 0..3
  const int c    = lane & 15;

  const int bh = blockIdx.y;
  const int q0 = blockIdx.x * QB;

  const float* Qb = q_g + (size_t)bh * SEQ * HD;
  const float* Kb = k_g + (size_t)bh * SEQ * HD;
  const float* Vb = v_g + (size_t)bh * SEQ * HD;
  float*       Ob = o_g + (size_t)bh * SEQ * HD;

  // reference does softmax((qk + mask) * (1/sqrt(D))); work in log2 units
  const float scale_l2e = 0.08838834764831845f * 1.44269504088896340f;

  // ---- Q fragments (A operand), held in registers for the whole kernel ----
  // lane holds Q[q0 + wid*16 + c][kd*32 + g*8 + j], j=0..7
  const int qrow = q0 + wid * 16 + c;
  bf16x8 qf[4];
#pragma unroll
  for (int kd = 0; kd < 4; ++kd) {
    const float* p = Qb + (size_t)qrow * HD + kd * 32 + g * 8;
    float4 a = *(const float4*)p;
    float4 b = *(const float4*)(p + 4);
    qf[kd] = bf16x8{(bf16_t)a.x, (bf16_t)a.y, (bf16_t)a.z, (bf16_t)a.w,
                    (bf16_t)b.x, (bf16_t)b.y, (bf16_t)b.z, (bf16_t)b.w};
  }

  f32x4 oacc[8];
#pragma unroll
  for (int n = 0; n < 8; ++n) oacc[n] = f32x4{0.f, 0.f, 0.f, 0.f};
  float mrow[4] = {-INFINITY, -INFINITY, -INFINITY, -INFINITY};
  float lrow[4] = {0.f, 0.f, 0.f, 0.f};

  char* Pw = ldsP[wid];

  for (int kt = 0; kt < SEQ / KVB; ++kt) {
    const int k0 = kt * KVB;

    // ---- mask prefetch (global, L3-resident; independent of LDS) ----
    float mv[4][4];
#pragma unroll
    for (int n = 0; n < 4; ++n)
#pragma unroll
      for (int jr = 0; jr < 4; ++jr) {
        const int qr = q0 + wid * 16 + g * 4 + jr;
        const int kc = k0 + n * 16 + c;
        mv[n][jr] = m_g[(size_t)qr * SEQ + kc];
      }

    __syncthreads();  // previous tile's LDS reads complete before overwrite

    // ---- stage K tile: coalesced float4 loads, b64 swizzled writes ----
#pragma unroll
    for (int i = 0; i < 8; ++i) {
      const int idx = tid + i * 256;   // 0..2047
      const int row = idx >> 5;        // k-row 0..63
      const int c4  = idx & 31;        // float4 column
      float4 v = *(const float4*)(Kb + (size_t)(k0 + row) * HD + c4 * 4);
      int byt = row * 256 + c4 * 8;
      byt ^= (row & 7) << 4;
      *(bf16x4*)(ldsK + byt) = bf16x4{(bf16_t)v.x, (bf16_t)v.y, (bf16_t)v.z, (bf16_t)v.w};
    }

    // ---- stage V^T: k = lane (d uniform per wave-instr) => conflict-free
    //      scalar scatter writes (bank = lane>>1 ^ const). Global reads are
    //      16B/lane across 64 rows; tile is fully consumed so no HBM overfetch.
#pragma unroll
    for (int i = 0; i < 8; ++i) {
      const int c4 = wid + i * 4;      // 0..31, disjoint across waves
      float4 v = *(const float4*)(Vb + (size_t)(k0 + lane) * HD + c4 * 4);
      float vv[4] = {v.x, v.y, v.z, v.w};
#pragma unroll
      for (int j = 0; j < 4; ++j) {
        const int d = c4 * 4 + j;
        int byt = d * 128 + lane * 2;
        byt ^= (d & 7) << 4;
        *(bf16_t*)(ldsV + byt) = (bf16_t)vv[j];
      }
    }

    __syncthreads();

    // ---- QK^T: 16x64 scores, 16 MFMAs ----
    f32x4 sacc[4];
#pragma unroll
    for (int n = 0; n < 4; ++n) sacc[n] = f32x4{0.f, 0.f, 0.f, 0.f};
#pragma unroll
    for (int kd = 0; kd < 4; ++kd) {
#pragma unroll
      for (int n = 0; n < 4; ++n) {
        const int krow = n * 16 + c;                    // key row = output col
        int byt = krow * 256 + (kd * 32 + g * 8) * 2;   // 16B, d-contiguous
        byt ^= (krow & 7) << 4;
        bf16x8 kf = *(const bf16x8*)(ldsK + byt);
        sacc[n] = __builtin_amdgcn_mfma_f32_16x16x32_bf16(qf[kd], kf, sacc[n], 0, 0, 0);
      }
    }

    // ---- logits in log2 units; wave-parallel online softmax ----
    float l2[4][4];
#pragma unroll
    for (int n = 0; n < 4; ++n)
#pragma unroll
      for (int jr = 0; jr < 4; ++jr)
        l2[n][jr] = (sacc[n][jr] + mv[n][jr]) * scale_l2e;

    float fac[4], mnew[4];
#pragma unroll
    for (int jr = 0; jr < 4; ++jr) {
      float mx = fmaxf(fmaxf(l2[0][jr], l2[1][jr]), fmaxf(l2[2][jr], l2[3][jr]));
#pragma unroll
      for (int msk = 1; msk <= 8; msk <<= 1)
        mx = fmaxf(mx, __shfl_xor(mx, msk, 64));        // stays in 16-lane group
      mnew[jr] = fmaxf(mrow[jr], mx);
      fac[jr]  = exp2f(mrow[jr] - mnew[jr]);            // first tile: exp2(-inf)=0
      mrow[jr] = mnew[jr];
    }

    float rsum[4] = {0.f, 0.f, 0.f, 0.f};
    bf16_t pb[4][4];
#pragma unroll
    for (int n = 0; n < 4; ++n)
#pragma unroll
      for (int jr = 0; jr < 4; ++jr) {
        const float p = exp2f(l2[n][jr] - mnew[jr]);
        rsum[jr] += p;
        pb[n][jr] = (bf16_t)p;
      }
#pragma unroll
    for (int jr = 0; jr < 4; ++jr) {
      float s = rsum[jr];
#pragma unroll
      for (int msk = 1; msk <= 8; msk <<= 1)
        s += __shfl_xor(s, msk, 64);
      lrow[jr] = lrow[jr] * fac[jr] + s;
    }

    // ---- rescale running O ----
#pragma unroll
    for (int n = 0; n < 8; ++n)
#pragma unroll
      for (int jr = 0; jr < 4; ++jr)
        oacc[n][jr] *= fac[jr];

    // ---- P -> per-wave LDS (re-layout for PV A operand), swizzled ----
#pragma unroll
    for (int n = 0; n < 4; ++n)
#pragma unroll
      for (int jr = 0; jr < 4; ++jr) {
        const int row = g * 4 + jr;        // q-local
        const int col = n * 16 + c;        // k-local
        int byt = row * 128 + col * 2;
        byt ^= (row & 7) << 4;
        *(bf16_t*)(Pw + byt) = pb[n][jr];
      }

    // ---- PV: O(16x128) += P(16x64) * V(64x128), 16 MFMAs ----
#pragma unroll
    for (int kd = 0; kd < 2; ++kd) {
      int abyt = c * 128 + (kd * 32 + g * 8) * 2;       // P row = c, k-contiguous
      abyt ^= (c & 7) << 4;
      bf16x8 pf = *(const bf16x8*)(Pw + abyt);
#pragma unroll
      for (int n = 0; n < 8; ++n) {
        const int d = n * 16 + c;                        // V^T row = output col
        int byt = d * 128 + (kd * 32 + g * 8) * 2;       // 16B, k-contiguous
        byt ^= (d & 7) << 4;
        bf16x8 vf = *(const bf16x8*)(ldsV + byt);
        oacc[n] = __builtin_amdgcn_mfma_f32_16x16x32_bf16(pf, vf, oacc[n], 0, 0, 0);
      }
    }
  }

  // ---- epilogue: O / l, coalesced fp32 stores ----
  float rinv[4];
#pragma unroll
  for (int jr = 0; jr < 4; ++jr) rinv[jr] = 1.f / lrow[jr];
#pragma unroll
  for (int n = 0; n < 8; ++n)
#pragma unroll
    for (int jr = 0; jr < 4; ++jr) {
      const int qr = q0 + wid * 16 + g * 4 + jr;
      Ob[(size_t)qr * HD + n * 16 + c] = oacc[n][jr] * rinv[jr];
    }
}

extern "C" void kernel_launch(void* const* d_in, const int* in_sizes, int n_in,
                              void* d_out, int out_size, void* d_ws, size_t ws_size,
                              hipStream_t stream) {
  (void)in_sizes; (void)n_in; (void)out_size; (void)d_ws; (void)ws_size;
  const float* Q = (const float*)d_in[0];
  const float* K = (const float*)d_in[1];
  const float* V = (const float*)d_in[2];
  const float* M = (const float*)d_in[3];
  float*       O = (float*)d_out;

  dim3 grid(SEQ / QB, 4 * 16);   // 32 q-tiles x 64 (b,h)
  attn_fwd<<<grid, 256, 0, stream>>>(Q, K, V, M, O);
}